// Round 10
// baseline (138.975 us; speedup 1.0000x reference)
//
#include <hip/hip_runtime.h>
#include <stdint.h>

#define B_ 2
#define S_ 2048
#define D_ 1024
#define H_ 16
#define HD_ 64
#define K_ 64

typedef __attribute__((ext_vector_type(8))) __bf16 bf16x8v;
typedef __attribute__((ext_vector_type(4))) float f32x4;
typedef __attribute__((ext_vector_type(8))) unsigned short ushort8v;

#define GLD_LDS16(g, l)                                                        \
  __builtin_amdgcn_global_load_lds(                                            \
      (const __attribute__((address_space(1))) void*)(g),                      \
      (__attribute__((address_space(3))) void*)(l), 16, 0, 0)

__device__ __forceinline__ float bf2f(unsigned short u) {
  union { unsigned u32; float f; } c;
  c.u32 = ((unsigned)u) << 16;
  return c.f;
}
__device__ __forceinline__ unsigned short f2bf(float f) {
  union { float f; unsigned u; } c;
  c.f = f;
  unsigned u = c.u;
  u += 0x7fffu + ((u >> 16) & 1u);  // RNE (finite inputs)
  return (unsigned short)(u >> 16);
}

// ------------- fused prep: cast x + transpose-cast both weights -------------
__global__ __launch_bounds__(256) void prep_fused(
    const float* __restrict__ x, unsigned short* __restrict__ x_bf,
    const float* __restrict__ Wqkv, unsigned short* __restrict__ wqkvT,
    const float* __restrict__ Wproj, unsigned short* __restrict__ wprojT) {
  __shared__ float tile[64][65];
  const int bid = blockIdx.x;
  const int t = threadIdx.x;

  if (bid < 4096) {
    const int i = bid * 256 + t;  // float4 index, n4 = 1048576
    float4 v = ((const float4*)x)[i];
    ushort4 o;
    o.x = f2bf(v.x); o.y = f2bf(v.y); o.z = f2bf(v.z); o.w = f2bf(v.w);
    ((ushort4*)x_bf)[i] = o;
    return;
  }

  const float* W;
  unsigned short* WT;
  int R, C, bx, by;
  if (bid < 4096 + 768) {
    const int b2 = bid - 4096;
    W = Wqkv; WT = wqkvT; R = D_; C = 3 * D_;
    by = b2 / 48; bx = b2 - by * 48;
  } else {
    const int b3 = bid - 4096 - 768;
    W = Wproj; WT = wprojT; R = D_; C = D_;
    by = b3 >> 4; bx = b3 & 15;
  }
  const int r0 = by * 64;
  const int c0 = bx * 64;
#pragma unroll
  for (int i = 0; i < 16; ++i) {
    int idx = t + i * 256;
    int rr = idx >> 6, cc = idx & 63;
    tile[rr][cc] = W[(size_t)(r0 + rr) * C + c0 + cc];
  }
  __syncthreads();
#pragma unroll
  for (int i = 0; i < 16; ++i) {
    int idx = t + i * 256;
    int rr = idx >> 6, cc = idx & 63;  // rr: row of WT (= col of W)
    WT[(size_t)(c0 + rr) * R + r0 + cc] = f2bf(tile[cc][rr]);
  }
}

// --- bf16 GEMM, 128x128 tile, BK=64, T2 swizzle + T3-min double buffer ------
// Issue-early pipeline (T3 minimum, m248v2): STAGE(next buf) BEFORE
// compute(cur buf), single __syncthreads per K-tile. The sync's vmcnt drain
// now waits on loads aged one full compute phase instead of zero-age loads.
// LDS 64 KB -> 2 blocks/CU; each wave self-covers latency with 32 MFMA.
template <bool OUT_F32>
__global__ __launch_bounds__(256) void gemm_bias(
    const unsigned short* __restrict__ A, const unsigned short* __restrict__ Bt,
    const float* __restrict__ bias, void* __restrict__ Cout,
    int M, int N, int Kd) {
  __shared__ unsigned short As[2][128 * 64];  // 16 KB x2
  __shared__ unsigned short Bs[2][128 * 64];  // 16 KB x2
  const int t = threadIdx.x;
  const int w = t >> 6;
  const int l = t & 63;
  const int m0 = blockIdx.y * 128;
  const int n0 = blockIdx.x * 128;
  const int wr = w >> 1, wc = w & 1;

  f32x4 acc[4][4] = {};

  // staging: granule g = i*256 + t -> row i*32 + (t>>3), col-block t&7.
  // Source col pre-swizzled by (row&7)*8 (rule #21: linear LDS dest).
  const int g_r = t >> 3;                                    // 0..31
  const int scol = ((t & 7) * 8) ^ ((g_r & 7) * 8);          // per-thread const
  char* asBase = (char*)As + w * 1024;
  char* bsBase = (char*)Bs + w * 1024;

  const int lr = l & 15;
  const int kq = (l >> 4) * 8;
  const int xr = (lr & 7) * 8;  // read-side XOR, per-thread const

#define STAGE_AB(kt, buf)                                                      \
  {                                                                            \
    _Pragma("unroll") for (int i = 0; i < 4; ++i)                              \
        GLD_LDS16(A + (size_t)(m0 + i * 32 + g_r) * Kd + (kt) * 64 + scol,     \
                  asBase + (buf) * 16384 + i * 4096);                          \
    _Pragma("unroll") for (int i = 0; i < 4; ++i)                              \
        GLD_LDS16(Bt + (size_t)(n0 + i * 32 + g_r) * Kd + (kt) * 64 + scol,    \
                  bsBase + (buf) * 16384 + i * 4096);                          \
  }

  const int KT = Kd >> 6;  // BK = 64
  STAGE_AB(0, 0);
  __syncthreads();

  int cur = 0;
  for (int kt = 0; kt < KT; ++kt) {
    if (kt + 1 < KT) STAGE_AB(kt + 1, cur ^ 1);  // issue-early prefetch

    bf16x8v af[4][2], bfv[4][2];
#pragma unroll
    for (int m = 0; m < 4; ++m) {
      const int row = wr * 64 + m * 16 + lr;
#pragma unroll
      for (int ks = 0; ks < 2; ++ks)
        af[m][ks] =
            *(const bf16x8v*)&As[cur][row * 64 + ((ks * 32 + kq) ^ xr)];
    }
#pragma unroll
    for (int n = 0; n < 4; ++n) {
      const int row = wc * 64 + n * 16 + lr;
#pragma unroll
      for (int ks = 0; ks < 2; ++ks)
        bfv[n][ks] =
            *(const bf16x8v*)&Bs[cur][row * 64 + ((ks * 32 + kq) ^ xr)];
    }
#pragma unroll
    for (int m = 0; m < 4; ++m)
#pragma unroll
      for (int n = 0; n < 4; ++n)
#pragma unroll
        for (int ks = 0; ks < 2; ++ks)
          acc[m][n] = __builtin_amdgcn_mfma_f32_16x16x32_bf16(
              af[m][ks], bfv[n][ks], acc[m][n], 0, 0, 0);

    __syncthreads();  // drains prefetch (aged one compute phase) + WAR-protect
    cur ^= 1;
  }
#undef STAGE_AB

  const int rbase = (l >> 4) * 4;
#pragma unroll
  for (int m = 0; m < 4; ++m) {
#pragma unroll
    for (int n = 0; n < 4; ++n) {
      const int gc = n0 + wc * 64 + n * 16 + lr;
      const float bv = bias[gc];
#pragma unroll
      for (int j = 0; j < 4; ++j) {
        const int gr = m0 + wr * 64 + m * 16 + rbase + j;
        float v = acc[m][n][j] + bv;
        if (OUT_F32)
          ((float*)Cout)[(size_t)gr * N + gc] = v;
        else
          ((unsigned short*)Cout)[(size_t)gr * N + gc] = f2bf(v);
      }
    }
  }
}

// ---------------- routed gather attention (v2-exact, 67us / 154MB config) ---
__global__ __launch_bounds__(256) void attn_kernel(
    const unsigned short* __restrict__ qkv, const int* __restrict__ routes,
    unsigned short* __restrict__ outp) {
  __shared__ float sc[16][68];       // padded: bank = (4*head + j) % 32
  __shared__ unsigned rtsoff[64];    // precomputed (b*S + r) * 3072
  __shared__ float pbuf[1024];       // cross-wave PV partials
  const int bs = blockIdx.x;
  const int b = bs >> 11;            // / S_
  const int s = bs & (S_ - 1);
  const int t = threadIdx.x;
  const int w = t >> 6, l = t & 63;
  const int kh2 = w >> 1, hh = w & 1;

  if (t < 64) {
    int r = routes[s * K_ + t];
    r = min(max(r, 0), S_ - 1);
    rtsoff[t] = (unsigned)(b * S_ + r) * 3072u;
  }
  __syncthreads();

  const unsigned colo = hh * 512 + l * 8;
  const int head = colo >> 6;
  const size_t rowbase = (size_t)bs * 3072;

  float q[8];
  {
    ushort8v u = *(const ushort8v*)(qkv + rowbase + colo);
#pragma unroll
    for (int i = 0; i < 8; ++i) q[i] = bf2f(u[i]) * 0.125f;  // 1/sqrt(64)
  }

  const unsigned kofs = 1024u + colo;
  const unsigned vofs = 2048u + colo;
  const int jbase = kh2 * 32;

  // scores
#pragma unroll 4
  for (int j2 = 0; j2 < 32; ++j2) {
    const int j = jbase + j2;
    ushort8v u = *(const ushort8v*)(qkv + (rtsoff[j] + kofs));
    float d = q[0] * bf2f(u[0]);
#pragma unroll
    for (int i = 1; i < 8; ++i) d += q[i] * bf2f(u[i]);
    d += __shfl_xor(d, 1);
    d += __shfl_xor(d, 2);
    d += __shfl_xor(d, 4);
    if ((l & 7) == 0) sc[head][j] = d;
  }
  __syncthreads();

  // softmax over K=64, 16 threads per head
  {
    const int h = t >> 4;
    const int l2 = t & 15;
    float v0 = sc[h][l2], v1 = sc[h][l2 + 16], v2 = sc[h][l2 + 32],
          v3 = sc[h][l2 + 48];
    float m = fmaxf(fmaxf(v0, v1), fmaxf(v2, v3));
    m = fmaxf(m, __shfl_xor(m, 1));
    m = fmaxf(m, __shfl_xor(m, 2));
    m = fmaxf(m, __shfl_xor(m, 4));
    m = fmaxf(m, __shfl_xor(m, 8));
    v0 = __expf(v0 - m); v1 = __expf(v1 - m);
    v2 = __expf(v2 - m); v3 = __expf(v3 - m);
    float ss = v0 + v1 + v2 + v3;
    ss += __shfl_xor(ss, 1);
    ss += __shfl_xor(ss, 2);
    ss += __shfl_xor(ss, 4);
    ss += __shfl_xor(ss, 8);
    float inv = 1.0f / ss;
    sc[h][l2] = v0 * inv;
    sc[h][l2 + 16] = v1 * inv;
    sc[h][l2 + 32] = v2 * inv;
    sc[h][l2 + 48] = v3 * inv;
  }
  __syncthreads();

  // PV
  float acc[8] = {};
#pragma unroll 4
  for (int j2 = 0; j2 < 32; ++j2) {
    const int j = jbase + j2;
    ushort8v u = *(const ushort8v*)(qkv + (rtsoff[j] + vofs));
    const float p = sc[head][j];
#pragma unroll
    for (int i = 0; i < 8; ++i) acc[i] += p * bf2f(u[i]);
  }

  if (kh2 == 1) {
    f32x4 a0 = {acc[0], acc[1], acc[2], acc[3]};
    f32x4 a1 = {acc[4], acc[5], acc[6], acc[7]};
    *(f32x4*)&pbuf[colo] = a0;
    *(f32x4*)&pbuf[colo + 4] = a1;
  }
  __syncthreads();
  if (kh2 == 0) {
    ushort8v o;
#pragma unroll
    for (int i = 0; i < 8; ++i) o[i] = f2bf(acc[i] + pbuf[colo + i]);
    *(ushort8v*)(outp + (size_t)bs * D_ + colo) = o;
  }
}

extern "C" void kernel_launch(void* const* d_in, const int* in_sizes, int n_in,
                              void* d_out, int out_size, void* d_ws,
                              size_t ws_size, hipStream_t stream) {
  const float* x = (const float*)d_in[0];
  const float* Wqkv = (const float*)d_in[1];
  const float* bqkv = (const float*)d_in[2];
  const float* Wproj = (const float*)d_in[3];
  const float* bproj = (const float*)d_in[4];
  const int* routes = (const int*)d_in[5];
  float* out = (float*)d_out;

  char* ws = (char*)d_ws;
  unsigned short* x_bf = (unsigned short*)(ws);                    //  8,388,608
  unsigned short* wqkvT = (unsigned short*)(ws + 8388608);         //  6,291,456
  unsigned short* wprojT = (unsigned short*)(ws + 14680064);       //  2,097,152
  unsigned short* qkv = (unsigned short*)(ws + 16777216);          // 25,165,824
  unsigned short* aout = (unsigned short*)(ws + 41943040);         //  8,388,608

  prep_fused<<<5120, 256, 0, stream>>>(x, x_bf, Wqkv, wqkvT, Wproj, wprojT);

  gemm_bias<false><<<dim3(3 * D_ / 128, B_ * S_ / 128), 256, 0, stream>>>(
      x_bf, wqkvT, bqkv, qkv, B_ * S_, 3 * D_, D_);
  attn_kernel<<<B_ * S_, 256, 0, stream>>>(qkv, routes, aout);
  gemm_bias<true><<<dim3(D_ / 128, B_ * S_ / 128), 256, 0, stream>>>(
      aout, wprojT, bproj, out, B_ * S_, D_, D_);
}

// Round 11
// 136.875 us; speedup vs baseline: 1.0153x; 1.0153x over previous
//
#include <hip/hip_runtime.h>
#include <stdint.h>

#define B_ 2
#define S_ 2048
#define D_ 1024
#define H_ 16
#define HD_ 64
#define K_ 64

typedef __attribute__((ext_vector_type(8))) __bf16 bf16x8v;
typedef __attribute__((ext_vector_type(4))) float f32x4;
typedef __attribute__((ext_vector_type(8))) unsigned short ushort8v;

#define GLD_LDS16(g, l)                                                        \
  __builtin_amdgcn_global_load_lds(                                            \
      (const __attribute__((address_space(1))) void*)(g),                      \
      (__attribute__((address_space(3))) void*)(l), 16, 0, 0)

__device__ __forceinline__ float bf2f(unsigned short u) {
  union { unsigned u32; float f; } c;
  c.u32 = ((unsigned)u) << 16;
  return c.f;
}
__device__ __forceinline__ unsigned short f2bf(float f) {
  union { float f; unsigned u; } c;
  c.f = f;
  unsigned u = c.u;
  u += 0x7fffu + ((u >> 16) & 1u);  // RNE (finite inputs)
  return (unsigned short)(u >> 16);
}

// ------------- fused prep: cast x + transpose-cast both weights -------------
__global__ __launch_bounds__(256) void prep_fused(
    const float* __restrict__ x, unsigned short* __restrict__ x_bf,
    const float* __restrict__ Wqkv, unsigned short* __restrict__ wqkvT,
    const float* __restrict__ Wproj, unsigned short* __restrict__ wprojT) {
  __shared__ float tile[64][65];
  const int bid = blockIdx.x;
  const int t = threadIdx.x;

  if (bid < 4096) {
    const int i = bid * 256 + t;  // float4 index, n4 = 1048576
    float4 v = ((const float4*)x)[i];
    ushort4 o;
    o.x = f2bf(v.x); o.y = f2bf(v.y); o.z = f2bf(v.z); o.w = f2bf(v.w);
    ((ushort4*)x_bf)[i] = o;
    return;
  }

  const float* W;
  unsigned short* WT;
  int R, C, bx, by;
  if (bid < 4096 + 768) {
    const int b2 = bid - 4096;
    W = Wqkv; WT = wqkvT; R = D_; C = 3 * D_;
    by = b2 / 48; bx = b2 - by * 48;
  } else {
    const int b3 = bid - 4096 - 768;
    W = Wproj; WT = wprojT; R = D_; C = D_;
    by = b3 >> 4; bx = b3 & 15;
  }
  const int r0 = by * 64;
  const int c0 = bx * 64;
#pragma unroll
  for (int i = 0; i < 16; ++i) {
    int idx = t + i * 256;
    int rr = idx >> 6, cc = idx & 63;
    tile[rr][cc] = W[(size_t)(r0 + rr) * C + c0 + cc];
  }
  __syncthreads();
#pragma unroll
  for (int i = 0; i < 16; ++i) {
    int idx = t + i * 256;
    int rr = idx >> 6, cc = idx & 63;  // rr: row of WT (= col of W)
    WT[(size_t)(c0 + rr) * R + r0 + cc] = f2bf(tile[cc][rr]);
  }
}

// --- bf16 GEMM, 128x128 tile, BK=32 DOUBLE-buffer (32 KB -> 3 blocks/CU) ----
// Issue-early: STAGE(kt+1 -> buf^1) BEFORE compute(buf), one __syncthreads
// per K-iter. The sync's vmcnt drain waits on loads aged one compute phase
// (16 MFMA + 8 ds_read), not zero-age -- r10's lesson applied WITHOUT the
// 64 KB occupancy cliff. Swizzle: source col ^ (row&3)*8, read col same XOR
// (both per-thread constants).
template <bool OUT_F32>
__global__ __launch_bounds__(256) void gemm_bias(
    const unsigned short* __restrict__ A, const unsigned short* __restrict__ Bt,
    const float* __restrict__ bias, void* __restrict__ Cout,
    int M, int N, int Kd) {
  __shared__ unsigned short As[2][128 * 32];  // 8 KB x2
  __shared__ unsigned short Bs[2][128 * 32];  // 8 KB x2
  const int t = threadIdx.x;
  const int w = t >> 6;
  const int l = t & 63;
  const int m0 = blockIdx.y * 128;
  const int n0 = blockIdx.x * 128;
  const int wr = w >> 1, wc = w & 1;

  f32x4 acc[4][4] = {};

  // staging: thread t writes LDS row t>>2, chunk t&3 (8 elems).
  // Source col pre-swizzled: LDS[r][c] = G[r][c ^ ((r&3)*8)].
  const int srow = t >> 2;                                   // 0..63
  const int scol = ((t & 3) * 8) ^ ((srow & 3) * 8);         // per-thread const
  const int wofs = w * 1024;                                 // byte offset

  const int lr = l & 15;
  const int kq = (l >> 4) * 8;
  const int kqs = kq ^ ((lr & 3) * 8);  // read col after swizzle, const

#define STAGE_AB(kt, buf)                                                      \
  {                                                                            \
    GLD_LDS16(A + (size_t)(m0 + srow) * Kd + (kt) * 32 + scol,                 \
              (char*)&As[buf][0] + wofs);                                      \
    GLD_LDS16(A + (size_t)(m0 + 64 + srow) * Kd + (kt) * 32 + scol,            \
              (char*)&As[buf][0] + wofs + 4096);                               \
    GLD_LDS16(Bt + (size_t)(n0 + srow) * Kd + (kt) * 32 + scol,                \
              (char*)&Bs[buf][0] + wofs);                                      \
    GLD_LDS16(Bt + (size_t)(n0 + 64 + srow) * Kd + (kt) * 32 + scol,           \
              (char*)&Bs[buf][0] + wofs + 4096);                               \
  }

  const int KT = Kd >> 5;  // BK = 32
  STAGE_AB(0, 0);
  __syncthreads();

  int cur = 0;
  for (int kt = 0; kt < KT; ++kt) {
    if (kt + 1 < KT) STAGE_AB(kt + 1, cur ^ 1);  // issue-early prefetch

    bf16x8v af[4], bfv[4];
#pragma unroll
    for (int m = 0; m < 4; ++m)
      af[m] = *(const bf16x8v*)&As[cur][(wr * 64 + m * 16 + lr) * 32 + kqs];
#pragma unroll
    for (int n = 0; n < 4; ++n)
      bfv[n] = *(const bf16x8v*)&Bs[cur][(wc * 64 + n * 16 + lr) * 32 + kqs];
#pragma unroll
    for (int m = 0; m < 4; ++m)
#pragma unroll
      for (int n = 0; n < 4; ++n)
        acc[m][n] = __builtin_amdgcn_mfma_f32_16x16x32_bf16(af[m], bfv[n],
                                                            acc[m][n], 0, 0, 0);

    __syncthreads();  // drains aged prefetch + WAR-protects buf[cur]
    cur ^= 1;
  }
#undef STAGE_AB

  const int rbase = (l >> 4) * 4;
#pragma unroll
  for (int m = 0; m < 4; ++m) {
#pragma unroll
    for (int n = 0; n < 4; ++n) {
      const int gc = n0 + wc * 64 + n * 16 + lr;
      const float bv = bias[gc];
#pragma unroll
      for (int j = 0; j < 4; ++j) {
        const int gr = m0 + wr * 64 + m * 16 + rbase + j;
        float v = acc[m][n][j] + bv;
        if (OUT_F32)
          ((float*)Cout)[(size_t)gr * N + gc] = v;
        else
          ((unsigned short*)Cout)[(size_t)gr * N + gc] = f2bf(v);
      }
    }
  }
}

// ---------------- routed gather attention (v2-exact, 67us / 154MB config) ---
__global__ __launch_bounds__(256) void attn_kernel(
    const unsigned short* __restrict__ qkv, const int* __restrict__ routes,
    unsigned short* __restrict__ outp) {
  __shared__ float sc[16][68];       // padded: bank = (4*head + j) % 32
  __shared__ unsigned rtsoff[64];    // precomputed (b*S + r) * 3072
  __shared__ float pbuf[1024];       // cross-wave PV partials
  const int bs = blockIdx.x;
  const int b = bs >> 11;            // / S_
  const int s = bs & (S_ - 1);
  const int t = threadIdx.x;
  const int w = t >> 6, l = t & 63;
  const int kh2 = w >> 1, hh = w & 1;

  if (t < 64) {
    int r = routes[s * K_ + t];
    r = min(max(r, 0), S_ - 1);
    rtsoff[t] = (unsigned)(b * S_ + r) * 3072u;
  }
  __syncthreads();

  const unsigned colo = hh * 512 + l * 8;
  const int head = colo >> 6;
  const size_t rowbase = (size_t)bs * 3072;

  float q[8];
  {
    ushort8v u = *(const ushort8v*)(qkv + rowbase + colo);
#pragma unroll
    for (int i = 0; i < 8; ++i) q[i] = bf2f(u[i]) * 0.125f;  // 1/sqrt(64)
  }

  const unsigned kofs = 1024u + colo;
  const unsigned vofs = 2048u + colo;
  const int jbase = kh2 * 32;

  // scores
#pragma unroll 4
  for (int j2 = 0; j2 < 32; ++j2) {
    const int j = jbase + j2;
    ushort8v u = *(const ushort8v*)(qkv + (rtsoff[j] + kofs));
    float d = q[0] * bf2f(u[0]);
#pragma unroll
    for (int i = 1; i < 8; ++i) d += q[i] * bf2f(u[i]);
    d += __shfl_xor(d, 1);
    d += __shfl_xor(d, 2);
    d += __shfl_xor(d, 4);
    if ((l & 7) == 0) sc[head][j] = d;
  }
  __syncthreads();

  // softmax over K=64, 16 threads per head
  {
    const int h = t >> 4;
    const int l2 = t & 15;
    float v0 = sc[h][l2], v1 = sc[h][l2 + 16], v2 = sc[h][l2 + 32],
          v3 = sc[h][l2 + 48];
    float m = fmaxf(fmaxf(v0, v1), fmaxf(v2, v3));
    m = fmaxf(m, __shfl_xor(m, 1));
    m = fmaxf(m, __shfl_xor(m, 2));
    m = fmaxf(m, __shfl_xor(m, 4));
    m = fmaxf(m, __shfl_xor(m, 8));
    v0 = __expf(v0 - m); v1 = __expf(v1 - m);
    v2 = __expf(v2 - m); v3 = __expf(v3 - m);
    float ss = v0 + v1 + v2 + v3;
    ss += __shfl_xor(ss, 1);
    ss += __shfl_xor(ss, 2);
    ss += __shfl_xor(ss, 4);
    ss += __shfl_xor(ss, 8);
    float inv = 1.0f / ss;
    sc[h][l2] = v0 * inv;
    sc[h][l2 + 16] = v1 * inv;
    sc[h][l2 + 32] = v2 * inv;
    sc[h][l2 + 48] = v3 * inv;
  }
  __syncthreads();

  // PV
  float acc[8] = {};
#pragma unroll 4
  for (int j2 = 0; j2 < 32; ++j2) {
    const int j = jbase + j2;
    ushort8v u = *(const ushort8v*)(qkv + (rtsoff[j] + vofs));
    const float p = sc[head][j];
#pragma unroll
    for (int i = 0; i < 8; ++i) acc[i] += p * bf2f(u[i]);
  }

  if (kh2 == 1) {
    f32x4 a0 = {acc[0], acc[1], acc[2], acc[3]};
    f32x4 a1 = {acc[4], acc[5], acc[6], acc[7]};
    *(f32x4*)&pbuf[colo] = a0;
    *(f32x4*)&pbuf[colo + 4] = a1;
  }
  __syncthreads();
  if (kh2 == 0) {
    ushort8v o;
#pragma unroll
    for (int i = 0; i < 8; ++i) o[i] = f2bf(acc[i] + pbuf[colo + i]);
    *(ushort8v*)(outp + (size_t)bs * D_ + colo) = o;
  }
}

extern "C" void kernel_launch(void* const* d_in, const int* in_sizes, int n_in,
                              void* d_out, int out_size, void* d_ws,
                              size_t ws_size, hipStream_t stream) {
  const float* x = (const float*)d_in[0];
  const float* Wqkv = (const float*)d_in[1];
  const float* bqkv = (const float*)d_in[2];
  const float* Wproj = (const float*)d_in[3];
  const float* bproj = (const float*)d_in[4];
  const int* routes = (const int*)d_in[5];
  float* out = (float*)d_out;

  char* ws = (char*)d_ws;
  unsigned short* x_bf = (unsigned short*)(ws);                    //  8,388,608
  unsigned short* wqkvT = (unsigned short*)(ws + 8388608);         //  6,291,456
  unsigned short* wprojT = (unsigned short*)(ws + 14680064);       //  2,097,152
  unsigned short* qkv = (unsigned short*)(ws + 16777216);          // 25,165,824
  unsigned short* aout = (unsigned short*)(ws + 41943040);         //  8,388,608

  prep_fused<<<5120, 256, 0, stream>>>(x, x_bf, Wqkv, wqkvT, Wproj, wprojT);

  gemm_bias<false><<<dim3(3 * D_ / 128, B_ * S_ / 128), 256, 0, stream>>>(
      x_bf, wqkvT, bqkv, qkv, B_ * S_, 3 * D_, D_);
  attn_kernel<<<B_ * S_, 256, 0, stream>>>(qkv, routes, aout);
  gemm_bias<true><<<dim3(D_ / 128, B_ * S_ / 128), 256, 0, stream>>>(
      aout, wprojT, bproj, out, B_ * S_, D_, D_);
}

// Round 12
// 136.166 us; speedup vs baseline: 1.0206x; 1.0052x over previous
//
#include <hip/hip_runtime.h>
#include <stdint.h>

#define B_ 2
#define S_ 2048
#define D_ 1024
#define H_ 16
#define HD_ 64
#define K_ 64

typedef __attribute__((ext_vector_type(8))) __bf16 bf16x8v;
typedef __attribute__((ext_vector_type(4))) float f32x4;
typedef __attribute__((ext_vector_type(8))) unsigned short ushort8v;

#define GLD_LDS16(g, l)                                                        \
  __builtin_amdgcn_global_load_lds(                                            \
      (const __attribute__((address_space(1))) void*)(g),                      \
      (__attribute__((address_space(3))) void*)(l), 16, 0, 0)

__device__ __forceinline__ float bf2f(unsigned short u) {
  union { unsigned u32; float f; } c;
  c.u32 = ((unsigned)u) << 16;
  return c.f;
}
__device__ __forceinline__ unsigned short f2bf(float f) {
  union { float f; unsigned u; } c;
  c.f = f;
  unsigned u = c.u;
  u += 0x7fffu + ((u >> 16) & 1u);  // RNE (finite inputs)
  return (unsigned short)(u >> 16);
}

// ------------- fused prep: cast x + transpose-cast both weights -------------
__global__ __launch_bounds__(256) void prep_fused(
    const float* __restrict__ x, unsigned short* __restrict__ x_bf,
    const float* __restrict__ Wqkv, unsigned short* __restrict__ wqkvT,
    const float* __restrict__ Wproj, unsigned short* __restrict__ wprojT) {
  __shared__ float tile[64][65];
  const int bid = blockIdx.x;
  const int t = threadIdx.x;

  if (bid < 4096) {
    const int i = bid * 256 + t;  // float4 index, n4 = 1048576
    float4 v = ((const float4*)x)[i];
    ushort4 o;
    o.x = f2bf(v.x); o.y = f2bf(v.y); o.z = f2bf(v.z); o.w = f2bf(v.w);
    ((ushort4*)x_bf)[i] = o;
    return;
  }

  const float* W;
  unsigned short* WT;
  int R, C, bx, by;
  if (bid < 4096 + 768) {
    const int b2 = bid - 4096;
    W = Wqkv; WT = wqkvT; R = D_; C = 3 * D_;
    by = b2 / 48; bx = b2 - by * 48;
  } else {
    const int b3 = bid - 4096 - 768;
    W = Wproj; WT = wprojT; R = D_; C = D_;
    by = b3 >> 4; bx = b3 & 15;
  }
  const int r0 = by * 64;
  const int c0 = bx * 64;
#pragma unroll
  for (int i = 0; i < 16; ++i) {
    int idx = t + i * 256;
    int rr = idx >> 6, cc = idx & 63;
    tile[rr][cc] = W[(size_t)(r0 + rr) * C + c0 + cc];
  }
  __syncthreads();
#pragma unroll
  for (int i = 0; i < 16; ++i) {
    int idx = t + i * 256;
    int rr = idx >> 6, cc = idx & 63;  // rr: row of WT (= col of W)
    WT[(size_t)(c0 + rr) * R + r0 + cc] = f2bf(tile[cc][rr]);
  }
}

// ------- bf16 GEMM, 128x128 tile, BK=64, T2 swizzle (r9-exact, best) --------
template <bool OUT_F32>
__global__ __launch_bounds__(256) void gemm_bias(
    const unsigned short* __restrict__ A, const unsigned short* __restrict__ Bt,
    const float* __restrict__ bias, void* __restrict__ Cout,
    int M, int N, int Kd) {
  __shared__ unsigned short As[128 * 64];  // 16 KB
  __shared__ unsigned short Bs[128 * 64];  // 16 KB
  const int t = threadIdx.x;
  const int w = t >> 6;
  const int l = t & 63;
  const int m0 = blockIdx.y * 128;
  const int n0 = blockIdx.x * 128;
  const int wr = w >> 1, wc = w & 1;

  f32x4 acc[4][4] = {};

  const int g_r = t >> 3;                                   // 0..31
  const int scol = ((t & 7) * 8) ^ ((g_r & 7) * 8);          // per-thread const
  char* asBase = (char*)As + w * 1024;
  char* bsBase = (char*)Bs + w * 1024;

  const int lr = l & 15;
  const int kq = (l >> 4) * 8;
  const int xr = (lr & 7) * 8;  // read-side XOR, per-thread const

  const int KT = Kd >> 6;  // BK = 64
  for (int kt = 0; kt < KT; ++kt) {
    const int k0 = kt << 6;
    {
#pragma unroll
      for (int i = 0; i < 4; ++i)
        GLD_LDS16(A + (size_t)(m0 + i * 32 + g_r) * Kd + k0 + scol,
                  asBase + i * 4096);
#pragma unroll
      for (int i = 0; i < 4; ++i)
        GLD_LDS16(Bt + (size_t)(n0 + i * 32 + g_r) * Kd + k0 + scol,
                  bsBase + i * 4096);
    }
    __syncthreads();
    bf16x8v af[4][2], bfv[4][2];
#pragma unroll
    for (int m = 0; m < 4; ++m) {
      const int row = wr * 64 + m * 16 + lr;
#pragma unroll
      for (int ks = 0; ks < 2; ++ks)
        af[m][ks] = *(const bf16x8v*)&As[row * 64 + ((ks * 32 + kq) ^ xr)];
    }
#pragma unroll
    for (int n = 0; n < 4; ++n) {
      const int row = wc * 64 + n * 16 + lr;
#pragma unroll
      for (int ks = 0; ks < 2; ++ks)
        bfv[n][ks] = *(const bf16x8v*)&Bs[row * 64 + ((ks * 32 + kq) ^ xr)];
    }
#pragma unroll
    for (int m = 0; m < 4; ++m)
#pragma unroll
      for (int n = 0; n < 4; ++n)
#pragma unroll
        for (int ks = 0; ks < 2; ++ks)
          acc[m][n] = __builtin_amdgcn_mfma_f32_16x16x32_bf16(
              af[m][ks], bfv[n][ks], acc[m][n], 0, 0, 0);
    __syncthreads();
  }

  const int rbase = (l >> 4) * 4;
#pragma unroll
  for (int m = 0; m < 4; ++m) {
#pragma unroll
    for (int n = 0; n < 4; ++n) {
      const int gc = n0 + wc * 64 + n * 16 + lr;
      const float bv = bias[gc];
#pragma unroll
      for (int j = 0; j < 4; ++j) {
        const int gr = m0 + wr * 64 + m * 16 + rbase + j;
        float v = acc[m][n][j] + bv;
        if (OUT_F32)
          ((float*)Cout)[(size_t)gr * N + gc] = v;
        else
          ((unsigned short*)Cout)[(size_t)gr * N + gc] = f2bf(v);
      }
    }
  }
}

// -------- routed gather attention (v2 compute + XCD batch partition) --------
// blockIdx remap so each XCD serves ONE batch (assumes round-robin
// blockIdx%8 -> XCD): b = bit2(id), s = (id>>3)*4 + (id&3)  [bijective].
// Per-XCD gather working set drops 32 MB -> 16 MB (K+V of one batch).
__global__ __launch_bounds__(256) void attn_kernel(
    const unsigned short* __restrict__ qkv, const int* __restrict__ routes,
    unsigned short* __restrict__ outp) {
  __shared__ float sc[16][68];       // padded: bank = (4*head + j) % 32
  __shared__ unsigned rtsoff[64];    // precomputed (b*S + r) * 3072
  __shared__ float pbuf[1024];       // cross-wave PV partials
  const int id = blockIdx.x;
  const int b = (id >> 2) & 1;               // XCDs 0-3 -> b=0, 4-7 -> b=1
  const int s = (id >> 3) * 4 + (id & 3);    // 0..2047, bijective per batch
  const int bs = b * S_ + s;
  const int t = threadIdx.x;
  const int w = t >> 6, l = t & 63;
  const int kh2 = w >> 1, hh = w & 1;

  if (t < 64) {
    int r = routes[s * K_ + t];
    r = min(max(r, 0), S_ - 1);
    rtsoff[t] = (unsigned)(b * S_ + r) * 3072u;
  }
  __syncthreads();

  const unsigned colo = hh * 512 + l * 8;
  const int head = colo >> 6;
  const size_t rowbase = (size_t)bs * 3072;

  float q[8];
  {
    ushort8v u = *(const ushort8v*)(qkv + rowbase + colo);
#pragma unroll
    for (int i = 0; i < 8; ++i) q[i] = bf2f(u[i]) * 0.125f;  // 1/sqrt(64)
  }

  const unsigned kofs = 1024u + colo;
  const unsigned vofs = 2048u + colo;
  const int jbase = kh2 * 32;

  // scores
#pragma unroll 4
  for (int j2 = 0; j2 < 32; ++j2) {
    const int j = jbase + j2;
    ushort8v u = *(const ushort8v*)(qkv + (rtsoff[j] + kofs));
    float d = q[0] * bf2f(u[0]);
#pragma unroll
    for (int i = 1; i < 8; ++i) d += q[i] * bf2f(u[i]);
    d += __shfl_xor(d, 1);
    d += __shfl_xor(d, 2);
    d += __shfl_xor(d, 4);
    if ((l & 7) == 0) sc[head][j] = d;
  }
  __syncthreads();

  // softmax over K=64, 16 threads per head
  {
    const int h = t >> 4;
    const int l2 = t & 15;
    float v0 = sc[h][l2], v1 = sc[h][l2 + 16], v2 = sc[h][l2 + 32],
          v3 = sc[h][l2 + 48];
    float m = fmaxf(fmaxf(v0, v1), fmaxf(v2, v3));
    m = fmaxf(m, __shfl_xor(m, 1));
    m = fmaxf(m, __shfl_xor(m, 2));
    m = fmaxf(m, __shfl_xor(m, 4));
    m = fmaxf(m, __shfl_xor(m, 8));
    v0 = __expf(v0 - m); v1 = __expf(v1 - m);
    v2 = __expf(v2 - m); v3 = __expf(v3 - m);
    float ss = v0 + v1 + v2 + v3;
    ss += __shfl_xor(ss, 1);
    ss += __shfl_xor(ss, 2);
    ss += __shfl_xor(ss, 4);
    ss += __shfl_xor(ss, 8);
    float inv = 1.0f / ss;
    sc[h][l2] = v0 * inv;
    sc[h][l2 + 16] = v1 * inv;
    sc[h][l2 + 32] = v2 * inv;
    sc[h][l2 + 48] = v3 * inv;
  }
  __syncthreads();

  // PV
  float acc[8] = {};
#pragma unroll 4
  for (int j2 = 0; j2 < 32; ++j2) {
    const int j = jbase + j2;
    ushort8v u = *(const ushort8v*)(qkv + (rtsoff[j] + vofs));
    const float p = sc[head][j];
#pragma unroll
    for (int i = 0; i < 8; ++i) acc[i] += p * bf2f(u[i]);
  }

  if (kh2 == 1) {
    f32x4 a0 = {acc[0], acc[1], acc[2], acc[3]};
    f32x4 a1 = {acc[4], acc[5], acc[6], acc[7]};
    *(f32x4*)&pbuf[colo] = a0;
    *(f32x4*)&pbuf[colo + 4] = a1;
  }
  __syncthreads();
  if (kh2 == 0) {
    ushort8v o;
#pragma unroll
    for (int i = 0; i < 8; ++i) o[i] = f2bf(acc[i] + pbuf[colo + i]);
    *(ushort8v*)(outp + (size_t)bs * D_ + colo) = o;
  }
}

extern "C" void kernel_launch(void* const* d_in, const int* in_sizes, int n_in,
                              void* d_out, int out_size, void* d_ws,
                              size_t ws_size, hipStream_t stream) {
  const float* x = (const float*)d_in[0];
  const float* Wqkv = (const float*)d_in[1];
  const float* bqkv = (const float*)d_in[2];
  const float* Wproj = (const float*)d_in[3];
  const float* bproj = (const float*)d_in[4];
  const int* routes = (const int*)d_in[5];
  float* out = (float*)d_out;

  char* ws = (char*)d_ws;
  unsigned short* x_bf = (unsigned short*)(ws);                    //  8,388,608
  unsigned short* wqkvT = (unsigned short*)(ws + 8388608);         //  6,291,456
  unsigned short* wprojT = (unsigned short*)(ws + 14680064);       //  2,097,152
  unsigned short* qkv = (unsigned short*)(ws + 16777216);          // 25,165,824
  unsigned short* aout = (unsigned short*)(ws + 41943040);         //  8,388,608

  prep_fused<<<5120, 256, 0, stream>>>(x, x_bf, Wqkv, wqkvT, Wproj, wprojT);

  gemm_bias<false><<<dim3(3 * D_ / 128, B_ * S_ / 128), 256, 0, stream>>>(
      x_bf, wqkvT, bqkv, qkv, B_ * S_, 3 * D_, D_);
  attn_kernel<<<B_ * S_, 256, 0, stream>>>(qkv, routes, aout);
  gemm_bias<true><<<dim3(D_ / 128, B_ * S_ / 128), 256, 0, stream>>>(
      aout, wprojT, bproj, out, B_ * S_, D_, D_);
}